// Round 1
// baseline (1033.057 us; speedup 1.0000x reference)
//
#include <hip/hip_runtime.h>
#include <hip/hip_bf16.h>

// Problem: single causal attention head.
// B=4, T=4096, C=1024, H=64. q=x@Wq, k=x@Wk, v=x@Wv;
// wei = softmax(mask(q k^T * C^-0.5)); out = wei @ v.  All fp32.
//
// Round 0: correct fp32 baseline. Two kernels:
//  1) qkv_proj: tiled GEMM [16384,1024]@[1024,64]x3, LDS-staged, scale folded into q.
//  2) flash_fwd: flash-attention, Qtile=32, Ktile=64, online softmax.

#define B_DIM 4
#define T_DIM 4096
#define C_DIM 1024
#define H_DIM 64
#define SCALE 0.03125f  // 1/sqrt(1024)

// ---------------------------------------------------------------------------
// QKV projection: block = 64 rows x 192 cols (q|k|v), K-chunks of 64 via LDS.
// ---------------------------------------------------------------------------
__global__ __launch_bounds__(256) void qkv_proj_kernel(
    const float* __restrict__ x,  const float* __restrict__ Wq,
    const float* __restrict__ Wk, const float* __restrict__ Wv,
    float* __restrict__ qo, float* __restrict__ ko, float* __restrict__ vo)
{
    __shared__ float xs[64][68];    // pad 68: 4 distinct banks for 4-row reads
    __shared__ float wsh[64][196];  // cols: [0,64)=Wq [64,128)=Wk [128,192)=Wv
    const int t  = threadIdx.x;
    const int r0 = blockIdx.x * 64;
    const int tr = t >> 4, tc = t & 15;   // 16x16 thread grid

    float acc[4][12];  // [row i][m*4+j], thread tile 4 rows x (3 mats x 4 cols)
    #pragma unroll
    for (int i = 0; i < 4; ++i)
        #pragma unroll
        for (int c = 0; c < 12; ++c) acc[i][c] = 0.f;

    for (int kc = 0; kc < C_DIM / 64; ++kc) {
        __syncthreads();  // previous compute done before overwriting LDS
        // stage x chunk (64x64) and W chunks (64x192), float4-coalesced
        int n = t;
        #pragma unroll
        for (int it = 0; it < 4; ++it, n += 256) {
            const int r = n >> 4, c4 = (n & 15) * 4;
            *(float4*)&xs[r][c4] =
                *(const float4*)&x[(size_t)(r0 + r) * C_DIM + kc * 64 + c4];
            const size_t gk = (size_t)(kc * 64 + r) * H_DIM;
            *(float4*)&wsh[r][      c4] = *(const float4*)&Wq[gk + c4];
            *(float4*)&wsh[r][ 64 + c4] = *(const float4*)&Wk[gk + c4];
            *(float4*)&wsh[r][128 + c4] = *(const float4*)&Wv[gk + c4];
        }
        __syncthreads();

        #pragma unroll 8
        for (int kk = 0; kk < 64; ++kk) {
            float xv[4];
            #pragma unroll
            for (int i = 0; i < 4; ++i) xv[i] = xs[tr * 4 + i][kk];
            float wv[12];
            #pragma unroll
            for (int m = 0; m < 3; ++m) {
                const float4 w4 = *(const float4*)&wsh[kk][m * 64 + tc * 4];
                wv[m * 4 + 0] = w4.x; wv[m * 4 + 1] = w4.y;
                wv[m * 4 + 2] = w4.z; wv[m * 4 + 3] = w4.w;
            }
            #pragma unroll
            for (int i = 0; i < 4; ++i)
                #pragma unroll
                for (int c = 0; c < 12; ++c) acc[i][c] += xv[i] * wv[c];
        }
    }

    // write q (scaled), k, v
    #pragma unroll
    for (int i = 0; i < 4; ++i) {
        const size_t R = (size_t)(r0 + tr * 4 + i) * H_DIM + tc * 4;
        float4 o;
        o.x = acc[i][0] * SCALE; o.y = acc[i][1] * SCALE;
        o.z = acc[i][2] * SCALE; o.w = acc[i][3] * SCALE;
        *(float4*)&qo[R] = o;
        o.x = acc[i][4]; o.y = acc[i][5]; o.z = acc[i][6]; o.w = acc[i][7];
        *(float4*)&ko[R] = o;
        o.x = acc[i][8]; o.y = acc[i][9]; o.z = acc[i][10]; o.w = acc[i][11];
        *(float4*)&vo[R] = o;
    }
}

// ---------------------------------------------------------------------------
// Flash attention fwd: Qtile=32 rows, Ktile=64 keys, online softmax.
// Grid: (T/32=128, B). Heavy (late) q-tiles launched first for load balance.
// ---------------------------------------------------------------------------
__global__ __launch_bounds__(256) void flash_fwd_kernel(
    const float* __restrict__ q, const float* __restrict__ k,
    const float* __restrict__ v, float* __restrict__ out)
{
    __shared__ float ks[64][68];
    __shared__ float vs[64][68];
    __shared__ float qs[32][68];
    __shared__ float ps[32][68];   // scores then probabilities, in place
    __shared__ float m_s[32], l_s[32], f_s[32];

    const int t   = threadIdx.x;
    const int b   = blockIdx.y;
    const int qt  = (gridDim.x - 1) - blockIdx.x;  // heavy tiles first
    const int bq0 = qt * 32;
    const size_t base = (size_t)b * T_DIM * H_DIM;
    const int sr = t >> 4, sc = t & 15;            // 16x16 thread grid

    // stage Q tile (already scaled by 1/32 in projection)
    for (int n = t; n < 512; n += 256) {
        const int r = n >> 4, c4 = (n & 15) * 4;
        *(float4*)&qs[r][c4] =
            *(const float4*)&q[base + (size_t)(bq0 + r) * H_DIM + c4];
    }
    if (t < 32) { m_s[t] = -1e30f; l_s[t] = 0.f; }
    float o_acc[2][4] = {{0.f,0.f,0.f,0.f},{0.f,0.f,0.f,0.f}};

    const int nkt = (bq0 + 31) / 64 + 1;
    for (int kt = 0; kt < nkt; ++kt) {
        __syncthreads();  // previous PV / q-stage done
        const int kg0 = kt * 64;
        int n = t;
        #pragma unroll
        for (int it = 0; it < 4; ++it, n += 256) {
            const int r = n >> 4, c4 = (n & 15) * 4;
            const size_t g = base + (size_t)(kg0 + r) * H_DIM + c4;
            *(float4*)&ks[r][c4] = *(const float4*)&k[g];
            *(float4*)&vs[r][c4] = *(const float4*)&v[g];
        }
        __syncthreads();

        // S = Q . K^T  (thread: 2 rows x 4 keys)
        float s[2][4] = {{0.f,0.f,0.f,0.f},{0.f,0.f,0.f,0.f}};
        for (int h = 0; h < 64; ++h) {
            float qv[2];
            qv[0] = qs[sr * 2 + 0][h];
            qv[1] = qs[sr * 2 + 1][h];
            float kv[4];
            #pragma unroll
            for (int jj = 0; jj < 4; ++jj) kv[jj] = ks[sc * 4 + jj][h];
            #pragma unroll
            for (int i = 0; i < 2; ++i)
                #pragma unroll
                for (int jj = 0; jj < 4; ++jj) s[i][jj] += qv[i] * kv[jj];
        }
        // causal mask + store to LDS
        #pragma unroll
        for (int i = 0; i < 2; ++i)
            #pragma unroll
            for (int jj = 0; jj < 4; ++jj) {
                const int rg = bq0 + sr * 2 + i, jg = kg0 + sc * 4 + jj;
                ps[sr * 2 + i][sc * 4 + jj] = (jg <= rg) ? s[i][jj] : -1e30f;
            }
        __syncthreads();

        // online softmax: 4 threads per row (rows 0..31 on threads 0..127)
        if (t < 128) {
            const int row = t >> 2, part = t & 3;
            float mloc = -1e30f;
            #pragma unroll
            for (int j = 0; j < 16; ++j)
                mloc = fmaxf(mloc, ps[row][part * 16 + j]);
            mloc = fmaxf(mloc, __shfl_xor(mloc, 1, 64));
            mloc = fmaxf(mloc, __shfl_xor(mloc, 2, 64));
            const float mnew = fmaxf(m_s[row], mloc);
            float lloc = 0.f;
            #pragma unroll
            for (int j = 0; j < 16; ++j) {
                const float p = __expf(ps[row][part * 16 + j] - mnew);
                ps[row][part * 16 + j] = p;
                lloc += p;
            }
            lloc += __shfl_xor(lloc, 1, 64);
            lloc += __shfl_xor(lloc, 2, 64);
            if (part == 0) {
                const float f = __expf(m_s[row] - mnew);  // 0 on first tile
                l_s[row] = l_s[row] * f + lloc;
                m_s[row] = mnew;
                f_s[row] = f;
            }
        }
        __syncthreads();

        // O = O*f + P.V  (thread: 2 rows x 4 h-cols)
        #pragma unroll
        for (int i = 0; i < 2; ++i) {
            const float fr = f_s[sr * 2 + i];
            #pragma unroll
            for (int jj = 0; jj < 4; ++jj) o_acc[i][jj] *= fr;
        }
        for (int j = 0; j < 64; ++j) {
            float pv[2];
            pv[0] = ps[sr * 2 + 0][j];
            pv[1] = ps[sr * 2 + 1][j];
            float vv[4];
            #pragma unroll
            for (int jj = 0; jj < 4; ++jj) vv[jj] = vs[j][sc * 4 + jj];
            #pragma unroll
            for (int i = 0; i < 2; ++i)
                #pragma unroll
                for (int jj = 0; jj < 4; ++jj) o_acc[i][jj] += pv[i] * vv[jj];
        }
    }

    // epilogue: normalize and store
    #pragma unroll
    for (int i = 0; i < 2; ++i) {
        const int r = sr * 2 + i;
        const float inv = 1.f / l_s[r];
        float4 o;
        o.x = o_acc[i][0] * inv; o.y = o_acc[i][1] * inv;
        o.z = o_acc[i][2] * inv; o.w = o_acc[i][3] * inv;
        *(float4*)&out[base + (size_t)(bq0 + r) * H_DIM + sc * 4] = o;
    }
}

// ---------------------------------------------------------------------------
extern "C" void kernel_launch(void* const* d_in, const int* in_sizes, int n_in,
                              void* d_out, int out_size, void* d_ws, size_t ws_size,
                              hipStream_t stream)
{
    const float* x  = (const float*)d_in[0];
    const float* Wq = (const float*)d_in[1];
    const float* Wk = (const float*)d_in[2];
    const float* Wv = (const float*)d_in[3];
    float* out = (float*)d_out;

    // workspace: q,k,v fp32 [B*T,H] = 4MB each (needs 12MB of ws)
    const size_t n_qkv = (size_t)B_DIM * T_DIM * H_DIM;
    float* qf = (float*)d_ws;
    float* kf = qf + n_qkv;
    float* vf = kf + n_qkv;

    hipLaunchKernelGGL(qkv_proj_kernel, dim3((B_DIM * T_DIM) / 64), dim3(256),
                       0, stream, x, Wq, Wk, Wv, qf, kf, vf);
    hipLaunchKernelGGL(flash_fwd_kernel, dim3(T_DIM / 32, B_DIM), dim3(256),
                       0, stream, qf, kf, vf, out);
}

// Round 2
// 218.700 us; speedup vs baseline: 4.7236x; 4.7236x over previous
//
#include <hip/hip_runtime.h>
#include <hip/hip_bf16.h>

// Single causal attention head. B=4, T=4096, C=1024, H=64, fp32 in/out.
// R1: flash attention rewritten on bf16 MFMA (16x16x32). qkv_proj still
// fp32 VALU but emits bf16 q (pre-scaled by C^-0.5), k, v into ws.

#define B_DIM 4
#define T_DIM 4096
#define C_DIM 1024
#define H_DIM 64
#define SCALE 0.03125f  // 1/sqrt(1024)

typedef __attribute__((ext_vector_type(8))) short bf8;    // 8 bf16 (4 VGPRs)
typedef __attribute__((ext_vector_type(4))) float f32x4;  // MFMA acc

__device__ __forceinline__ ushort f2bf(float f) {
    union { float f; uint u; } x; x.f = f;
    const uint u = x.u;
    return (ushort)((u + 0x7FFFu + ((u >> 16) & 1u)) >> 16);  // RNE
}

// ---------------------------------------------------------------------------
// QKV projection: block = 64 rows x 192 cols (q|k|v), K-chunks of 64 via LDS.
// fp32 accumulate; bf16 outputs (q pre-scaled).
// ---------------------------------------------------------------------------
__global__ __launch_bounds__(256) void qkv_proj_kernel(
    const float* __restrict__ x,  const float* __restrict__ Wq,
    const float* __restrict__ Wk, const float* __restrict__ Wv,
    ushort* __restrict__ qo, ushort* __restrict__ ko, ushort* __restrict__ vo)
{
    __shared__ float xs[64][68];
    __shared__ float wsh[64][196];
    const int t  = threadIdx.x;
    const int r0 = blockIdx.x * 64;
    const int tr = t >> 4, tc = t & 15;

    float acc[4][12];
    #pragma unroll
    for (int i = 0; i < 4; ++i)
        #pragma unroll
        for (int c = 0; c < 12; ++c) acc[i][c] = 0.f;

    for (int kc = 0; kc < C_DIM / 64; ++kc) {
        __syncthreads();
        int n = t;
        #pragma unroll
        for (int it = 0; it < 4; ++it, n += 256) {
            const int r = n >> 4, c4 = (n & 15) * 4;
            *(float4*)&xs[r][c4] =
                *(const float4*)&x[(size_t)(r0 + r) * C_DIM + kc * 64 + c4];
            const size_t gk = (size_t)(kc * 64 + r) * H_DIM;
            *(float4*)&wsh[r][      c4] = *(const float4*)&Wq[gk + c4];
            *(float4*)&wsh[r][ 64 + c4] = *(const float4*)&Wk[gk + c4];
            *(float4*)&wsh[r][128 + c4] = *(const float4*)&Wv[gk + c4];
        }
        __syncthreads();

        #pragma unroll 8
        for (int kk = 0; kk < 64; ++kk) {
            float xv[4];
            #pragma unroll
            for (int i = 0; i < 4; ++i) xv[i] = xs[tr * 4 + i][kk];
            float wv[12];
            #pragma unroll
            for (int m = 0; m < 3; ++m) {
                const float4 w4 = *(const float4*)&wsh[kk][m * 64 + tc * 4];
                wv[m * 4 + 0] = w4.x; wv[m * 4 + 1] = w4.y;
                wv[m * 4 + 2] = w4.z; wv[m * 4 + 3] = w4.w;
            }
            #pragma unroll
            for (int i = 0; i < 4; ++i)
                #pragma unroll
                for (int c = 0; c < 12; ++c) acc[i][c] += xv[i] * wv[c];
        }
    }

    #pragma unroll
    for (int i = 0; i < 4; ++i) {
        const size_t R = (size_t)(r0 + tr * 4 + i) * H_DIM + tc * 4;
        ushort4 o;
        o.x = f2bf(acc[i][0] * SCALE); o.y = f2bf(acc[i][1] * SCALE);
        o.z = f2bf(acc[i][2] * SCALE); o.w = f2bf(acc[i][3] * SCALE);
        *(ushort4*)&qo[R] = o;
        o.x = f2bf(acc[i][4]); o.y = f2bf(acc[i][5]);
        o.z = f2bf(acc[i][6]); o.w = f2bf(acc[i][7]);
        *(ushort4*)&ko[R] = o;
        o.x = f2bf(acc[i][8]); o.y = f2bf(acc[i][9]);
        o.z = f2bf(acc[i][10]); o.w = f2bf(acc[i][11]);
        *(ushort4*)&vo[R] = o;
    }
}

// ---------------------------------------------------------------------------
// MFMA flash attention. Block = 4 waves x 16 q-rows (QBLK=64), KBLK=64.
// Grid (64, B), heavy q-tiles first. LDS stride 72 elems = 144 B (16B-aligned
// b128, conflict-free quarter-wave bank map 4*lid mod 32).
// ---------------------------------------------------------------------------
#define KP 72

__global__ __launch_bounds__(256) void flash_mfma_kernel(
    const ushort* __restrict__ q, const ushort* __restrict__ k,
    const ushort* __restrict__ v, float* __restrict__ out)
{
    __shared__ ushort ks[64][KP];
    __shared__ ushort vt[64][KP];      // vt[h][j] = V[j][h]
    __shared__ ushort ps[4][16][KP];   // per-wave P tile (bf16)

    const int t    = threadIdx.x;
    const int lane = t & 63, wave = t >> 6;
    const int grp  = lane >> 4, lid = lane & 15;
    const int b    = blockIdx.y;
    const int qt   = (gridDim.x - 1) - blockIdx.x;  // heavy first
    const int bq0  = qt * 64;
    const size_t base = (size_t)b * T_DIM * H_DIM;

    // Q fragments: A[row=lid][k=grp*8+i (+h0)], kept in regs for all k-tiles
    const size_t qoff = base + (size_t)(bq0 + wave * 16 + lid) * H_DIM;
    bf8 qf0 = *(const bf8*)&q[qoff + grp * 8];
    bf8 qf1 = *(const bf8*)&q[qoff + 32 + grp * 8];

    f32x4 o_acc[4] = {};      // 4 h-tiles of 16x16, rows grp*4+r
    float m_r[4], l_r[4];
    #pragma unroll
    for (int r = 0; r < 4; ++r) { m_r[r] = -1e30f; l_r[r] = 0.f; }

    const int nkt = qt + 1;
    for (int kt64 = 0; kt64 < nkt; ++kt64) {
        const int kg0 = kt64 * 64;
        __syncthreads();  // prev iter's LDS reads done
        {   // stage K tile (rows kg0..+64) — coalesced b128 copies
            int n = t;
            #pragma unroll
            for (int it = 0; it < 2; ++it, n += 256) {
                const int r = n >> 3, c8 = (n & 7) * 8;
                *(bf8*)&ks[r][c8] =
                    *(const bf8*)&k[base + (size_t)(kg0 + r) * H_DIM + c8];
            }
            // stage V transposed: thread owns (j0,j0+1) x 8 h-cols
            const int j0 = (t & 31) * 2, c8 = (t >> 5) * 8;
            const bf8 v0 = *(const bf8*)&v[base + (size_t)(kg0 + j0) * H_DIM + c8];
            const bf8 v1 = *(const bf8*)&v[base + (size_t)(kg0 + j0 + 1) * H_DIM + c8];
            #pragma unroll
            for (int i = 0; i < 8; ++i) {
                const uint pk = (uint)(ushort)v0[i] | ((uint)(ushort)v1[i] << 16);
                *(uint*)&vt[c8 + i][j0] = pk;
            }
        }
        __syncthreads();

        // S = Q K^T : 4 k-subtiles of 16, K=64 via 2 MFMAs each
        f32x4 s[4];
        #pragma unroll
        for (int kt = 0; kt < 4; ++kt) {
            const bf8 kf0 = *(const bf8*)&ks[kt * 16 + lid][grp * 8];
            const bf8 kf1 = *(const bf8*)&ks[kt * 16 + lid][32 + grp * 8];
            f32x4 acc = {0.f, 0.f, 0.f, 0.f};
            acc = __builtin_amdgcn_mfma_f32_16x16x32_bf16(qf0, kf0, acc, 0, 0, 0);
            acc = __builtin_amdgcn_mfma_f32_16x16x32_bf16(qf1, kf1, acc, 0, 0, 0);
            s[kt] = acc;
        }

        // causal mask — only the diagonal k-tile needs it
        if (kt64 == nkt - 1) {
            const int row_g = bq0 + wave * 16 + grp * 4;
            #pragma unroll
            for (int kt = 0; kt < 4; ++kt) {
                const int col_g = kg0 + kt * 16 + lid;
                #pragma unroll
                for (int r = 0; r < 4; ++r)
                    if (col_g > row_g + r) s[kt][r] = -1e30f;
            }
        }

        // online softmax (rows = grp*4+r, cols spread over 16-lane group)
        #pragma unroll
        for (int r = 0; r < 4; ++r) {
            float m0 = fmaxf(fmaxf(s[0][r], s[1][r]), fmaxf(s[2][r], s[3][r]));
            m0 = fmaxf(m0, __shfl_xor(m0, 1));
            m0 = fmaxf(m0, __shfl_xor(m0, 2));
            m0 = fmaxf(m0, __shfl_xor(m0, 4));
            m0 = fmaxf(m0, __shfl_xor(m0, 8));
            const float mnew = fmaxf(m_r[r], m0);
            const float f = __expf(m_r[r] - mnew);
            m_r[r] = mnew;
            float lsum = 0.f;
            #pragma unroll
            for (int kt = 0; kt < 4; ++kt) {
                const float p = __expf(s[kt][r] - mnew);
                s[kt][r] = p;
                lsum += p;
            }
            lsum += __shfl_xor(lsum, 1);
            lsum += __shfl_xor(lsum, 2);
            lsum += __shfl_xor(lsum, 4);
            lsum += __shfl_xor(lsum, 8);
            l_r[r] = l_r[r] * f + lsum;
            #pragma unroll
            for (int ht = 0; ht < 4; ++ht) o_acc[ht][r] *= f;
        }

        // P -> LDS (bf16, per-wave region), C-layout write: row grp*4+r, col kt*16+lid
        #pragma unroll
        for (int kt = 0; kt < 4; ++kt)
            #pragma unroll
            for (int r = 0; r < 4; ++r)
                ps[wave][grp * 4 + r][kt * 16 + lid] = f2bf(s[kt][r]);

        // PV: A = P[row=lid][k=grp*8+i(+32)], B = V[k][col=lid] via vt
        const bf8 pa0 = *(const bf8*)&ps[wave][lid][grp * 8];
        const bf8 pa1 = *(const bf8*)&ps[wave][lid][32 + grp * 8];
        #pragma unroll
        for (int ht = 0; ht < 4; ++ht) {
            const bf8 vb0 = *(const bf8*)&vt[ht * 16 + lid][grp * 8];
            const bf8 vb1 = *(const bf8*)&vt[ht * 16 + lid][32 + grp * 8];
            o_acc[ht] = __builtin_amdgcn_mfma_f32_16x16x32_bf16(pa0, vb0, o_acc[ht], 0, 0, 0);
            o_acc[ht] = __builtin_amdgcn_mfma_f32_16x16x32_bf16(pa1, vb1, o_acc[ht], 0, 0, 0);
        }
    }

    // epilogue: normalize, fp32 store (64B contiguous per (r,ht) quarter-wave)
    #pragma unroll
    for (int r = 0; r < 4; ++r) {
        const float inv = 1.f / l_r[r];
        const size_t rowoff = base + (size_t)(bq0 + wave * 16 + grp * 4 + r) * H_DIM;
        #pragma unroll
        for (int ht = 0; ht < 4; ++ht)
            out[rowoff + ht * 16 + lid] = o_acc[ht][r] * inv;
    }
}

// ---------------------------------------------------------------------------
extern "C" void kernel_launch(void* const* d_in, const int* in_sizes, int n_in,
                              void* d_out, int out_size, void* d_ws, size_t ws_size,
                              hipStream_t stream)
{
    const float* x  = (const float*)d_in[0];
    const float* Wq = (const float*)d_in[1];
    const float* Wk = (const float*)d_in[2];
    const float* Wv = (const float*)d_in[3];
    float* out = (float*)d_out;

    // ws: q,k,v bf16 [B*T, H] = 2MB each
    const size_t n_qkv = (size_t)B_DIM * T_DIM * H_DIM;
    ushort* qb = (ushort*)d_ws;
    ushort* kb = qb + n_qkv;
    ushort* vb = kb + n_qkv;

    hipLaunchKernelGGL(qkv_proj_kernel, dim3((B_DIM * T_DIM) / 64), dim3(256),
                       0, stream, x, Wq, Wk, Wv, qb, kb, vb);
    hipLaunchKernelGGL(flash_mfma_kernel, dim3(T_DIM / 64, B_DIM), dim3(256),
                       0, stream, qb, kb, vb, out);
}

// Round 3
// 95.975 us; speedup vs baseline: 10.7638x; 2.2787x over previous
//
#include <hip/hip_runtime.h>
#include <hip/hip_bf16.h>

// Single causal attention head. B=4, T=4096, C=1024, H=64, fp32 in/out.
// R2: (1) split-K flash-decoding for occupancy (tiered on ws_size),
//     (2) MFMA bf16 qkv projection with pre-transposed W^T.

#define B_DIM 4
#define T_DIM 4096
#define C_DIM 1024
#define H_DIM 64
#define SCALE 0.03125f  // 1/sqrt(1024)
#define KP 72           // LDS stride (elems): 144B, 16B-aligned, 2-way-free

typedef __attribute__((ext_vector_type(8))) short bf8;    // 8 bf16
typedef __attribute__((ext_vector_type(4))) float f32x4;  // MFMA acc

__device__ __forceinline__ ushort f2bf(float f) {
    union { float f; uint u; } x; x.f = f;
    const uint u = x.u;
    return (ushort)((u + 0x7FFFu + ((u >> 16) & 1u)) >> 16);  // RNE
}

// ---------------------------------------------------------------------------
// W^T pre-pass: wtg[col][k], col 0..191 = (Wq|Wk|Wv) columns, bf16.
// ---------------------------------------------------------------------------
__global__ __launch_bounds__(256) void wt_kernel(
    const float* __restrict__ Wq, const float* __restrict__ Wk,
    const float* __restrict__ Wv, ushort* __restrict__ wtg)
{
    const int id  = blockIdx.x * 256 + threadIdx.x;  // 24576 total
    const int col = id >> 7;                          // 0..191
    const int k8  = (id & 127) * 8;                   // 0..1016
    const int m   = col >> 6, lc = col & 63;
    const float* W = (m == 0) ? Wq : (m == 1) ? Wk : Wv;
    ushort o[8];
    #pragma unroll
    for (int i = 0; i < 8; ++i)
        o[i] = f2bf(W[(size_t)(k8 + i) * H_DIM + lc]);
    *(bf8*)&wtg[(size_t)col * C_DIM + k8] = *(bf8*)o;
}

// ---------------------------------------------------------------------------
// QKV projection, bf16 MFMA. Block = 4 waves; tile M=32 rows x N=192 cols.
// Wave w owns cols [w*48, w*48+48) x 32 rows (2 row-subtiles x 3 col-subtiles).
// K-loop: 16 chunks of 64; x converted fp32->bf16 while staging.
// ---------------------------------------------------------------------------
__global__ __launch_bounds__(256) void qkv_mfma_kernel(
    const float* __restrict__ x, const ushort* __restrict__ wtg,
    ushort* __restrict__ qo, ushort* __restrict__ ko, ushort* __restrict__ vo)
{
    __shared__ ushort xs[32][KP];
    __shared__ ushort wts[192][KP];
    const int t    = threadIdx.x;
    const int lane = t & 63, wave = t >> 6;
    const int grp  = lane >> 4, lid = lane & 15;
    const int r0   = blockIdx.x * 32;

    f32x4 acc[2][3] = {};

    for (int kc = 0; kc < C_DIM / 64; ++kc) {
        __syncthreads();
        {   // stage x chunk 32x64 (fp32 -> bf16): 1 bf8 per thread
            const int r = t >> 3, c = (t & 7) * 8;
            const float4 a = *(const float4*)&x[(size_t)(r0 + r) * C_DIM + kc * 64 + c];
            const float4 b = *(const float4*)&x[(size_t)(r0 + r) * C_DIM + kc * 64 + c + 4];
            ushort p[8];
            p[0] = f2bf(a.x); p[1] = f2bf(a.y); p[2] = f2bf(a.z); p[3] = f2bf(a.w);
            p[4] = f2bf(b.x); p[5] = f2bf(b.y); p[6] = f2bf(b.z); p[7] = f2bf(b.w);
            *(bf8*)&xs[r][c] = *(bf8*)p;
        }
        {   // stage W^T chunk 192x64 (bf16 copy): 6 bf8 per thread
            #pragma unroll
            for (int it = 0; it < 6; ++it) {
                const int n = t + it * 256;
                const int col = n >> 3, c = (n & 7) * 8;
                *(bf8*)&wts[col][c] =
                    *(const bf8*)&wtg[(size_t)col * C_DIM + kc * 64 + c];
            }
        }
        __syncthreads();

        #pragma unroll
        for (int ks = 0; ks < 2; ++ks) {
            const bf8 a0 = *(const bf8*)&xs[lid][ks * 32 + grp * 8];
            const bf8 a1 = *(const bf8*)&xs[16 + lid][ks * 32 + grp * 8];
            #pragma unroll
            for (int j = 0; j < 3; ++j) {
                const int ct = wave * 3 + j;
                const bf8 bb = *(const bf8*)&wts[ct * 16 + lid][ks * 32 + grp * 8];
                acc[0][j] = __builtin_amdgcn_mfma_f32_16x16x32_bf16(a0, bb, acc[0][j], 0, 0, 0);
                acc[1][j] = __builtin_amdgcn_mfma_f32_16x16x32_bf16(a1, bb, acc[1][j], 0, 0, 0);
            }
        }
    }

    // epilogue: C map col=lid, row=grp*4+reg
    #pragma unroll
    for (int rt = 0; rt < 2; ++rt)
        #pragma unroll
        for (int j = 0; j < 3; ++j) {
            const int ct = wave * 3 + j;
            const int m = ct >> 2, lc = (ct & 3) * 16 + lid;
            ushort* dst = (m == 0) ? qo : (m == 1) ? ko : vo;
            const float sc = (m == 0) ? SCALE : 1.f;
            #pragma unroll
            for (int r = 0; r < 4; ++r) {
                const int row = r0 + rt * 16 + grp * 4 + r;
                dst[(size_t)row * H_DIM + lc] = f2bf(acc[rt][j][r] * sc);
            }
        }
}

// ---------------------------------------------------------------------------
// Split-K MFMA flash. Grid (nslots, 64, 4). Block = 4 waves x 16 q-rows.
// Chunk c covers k-tiles [c*S, min((c+1)*S, qt+1)). direct=1 -> normalize
// and write out; else write unnormalized partial O + m,l for combine pass.
// ---------------------------------------------------------------------------
__global__ __launch_bounds__(256) void flash_mfma_kernel(
    const ushort* __restrict__ q, const ushort* __restrict__ k,
    const ushort* __restrict__ v, float* __restrict__ pO,
    float* __restrict__ pm, float* __restrict__ pl,
    float* __restrict__ out, int S, int nslots, int direct)
{
    const int qt = 63 - blockIdx.y;          // heavy q-tiles first
    const int c  = blockIdx.x;
    const int kt_begin = c * S;
    const int kt_end   = min((c + 1) * S, qt + 1);
    if (kt_begin >= kt_end) return;          // inactive chunk (block-uniform)

    __shared__ ushort ks[64][KP];
    __shared__ ushort vt[64][KP];            // vt[h][j] = V[j][h]
    __shared__ ushort ps[4][16][KP];         // per-wave P tile

    const int t    = threadIdx.x;
    const int lane = t & 63, wave = t >> 6;
    const int grp  = lane >> 4, lid = lane & 15;
    const int b    = blockIdx.z;
    const int bq0  = qt * 64;
    const size_t base = (size_t)b * T_DIM * H_DIM;

    const size_t qoff = base + (size_t)(bq0 + wave * 16 + lid) * H_DIM;
    const bf8 qf0 = *(const bf8*)&q[qoff + grp * 8];
    const bf8 qf1 = *(const bf8*)&q[qoff + 32 + grp * 8];

    f32x4 o_acc[4] = {};
    float m_r[4], l_r[4];
    #pragma unroll
    for (int r = 0; r < 4; ++r) { m_r[r] = -1e30f; l_r[r] = 0.f; }

    for (int kt64 = kt_begin; kt64 < kt_end; ++kt64) {
        const int kg0 = kt64 * 64;
        __syncthreads();
        {   // stage K (row-major) and V (transposed)
            int n = t;
            #pragma unroll
            for (int it = 0; it < 2; ++it, n += 256) {
                const int r = n >> 3, c8 = (n & 7) * 8;
                *(bf8*)&ks[r][c8] =
                    *(const bf8*)&k[base + (size_t)(kg0 + r) * H_DIM + c8];
            }
            const int j0 = (t & 31) * 2, c8 = (t >> 5) * 8;
            const bf8 v0 = *(const bf8*)&v[base + (size_t)(kg0 + j0) * H_DIM + c8];
            const bf8 v1 = *(const bf8*)&v[base + (size_t)(kg0 + j0 + 1) * H_DIM + c8];
            #pragma unroll
            for (int i = 0; i < 8; ++i) {
                const uint pk = (uint)(ushort)v0[i] | ((uint)(ushort)v1[i] << 16);
                *(uint*)&vt[c8 + i][j0] = pk;
            }
        }
        __syncthreads();

        // S = Q K^T
        f32x4 s[4];
        #pragma unroll
        for (int kt = 0; kt < 4; ++kt) {
            const bf8 kf0 = *(const bf8*)&ks[kt * 16 + lid][grp * 8];
            const bf8 kf1 = *(const bf8*)&ks[kt * 16 + lid][32 + grp * 8];
            f32x4 a = {0.f, 0.f, 0.f, 0.f};
            a = __builtin_amdgcn_mfma_f32_16x16x32_bf16(qf0, kf0, a, 0, 0, 0);
            a = __builtin_amdgcn_mfma_f32_16x16x32_bf16(qf1, kf1, a, 0, 0, 0);
            s[kt] = a;
        }

        if (kt64 == qt) {  // diagonal tile: causal mask
            const int row_g = bq0 + wave * 16 + grp * 4;
            #pragma unroll
            for (int kt = 0; kt < 4; ++kt) {
                const int col_g = kg0 + kt * 16 + lid;
                #pragma unroll
                for (int r = 0; r < 4; ++r)
                    if (col_g > row_g + r) s[kt][r] = -1e30f;
            }
        }

        // online softmax
        #pragma unroll
        for (int r = 0; r < 4; ++r) {
            float m0 = fmaxf(fmaxf(s[0][r], s[1][r]), fmaxf(s[2][r], s[3][r]));
            m0 = fmaxf(m0, __shfl_xor(m0, 1));
            m0 = fmaxf(m0, __shfl_xor(m0, 2));
            m0 = fmaxf(m0, __shfl_xor(m0, 4));
            m0 = fmaxf(m0, __shfl_xor(m0, 8));
            const float mnew = fmaxf(m_r[r], m0);
            const float f = __expf(m_r[r] - mnew);
            m_r[r] = mnew;
            float lsum = 0.f;
            #pragma unroll
            for (int kt = 0; kt < 4; ++kt) {
                const float p = __expf(s[kt][r] - mnew);
                s[kt][r] = p;
                lsum += p;
            }
            lsum += __shfl_xor(lsum, 1);
            lsum += __shfl_xor(lsum, 2);
            lsum += __shfl_xor(lsum, 4);
            lsum += __shfl_xor(lsum, 8);
            l_r[r] = l_r[r] * f + lsum;
            #pragma unroll
            for (int ht = 0; ht < 4; ++ht) o_acc[ht][r] *= f;
        }

        // P -> LDS (bf16) then PV
        #pragma unroll
        for (int kt = 0; kt < 4; ++kt)
            #pragma unroll
            for (int r = 0; r < 4; ++r)
                ps[wave][grp * 4 + r][kt * 16 + lid] = f2bf(s[kt][r]);

        const bf8 pa0 = *(const bf8*)&ps[wave][lid][grp * 8];
        const bf8 pa1 = *(const bf8*)&ps[wave][lid][32 + grp * 8];
        #pragma unroll
        for (int ht = 0; ht < 4; ++ht) {
            const bf8 vb0 = *(const bf8*)&vt[ht * 16 + lid][grp * 8];
            const bf8 vb1 = *(const bf8*)&vt[ht * 16 + lid][32 + grp * 8];
            o_acc[ht] = __builtin_amdgcn_mfma_f32_16x16x32_bf16(pa0, vb0, o_acc[ht], 0, 0, 0);
            o_acc[ht] = __builtin_amdgcn_mfma_f32_16x16x32_bf16(pa1, vb1, o_acc[ht], 0, 0, 0);
        }
    }

    if (direct) {
        #pragma unroll
        for (int r = 0; r < 4; ++r) {
            const float inv = 1.f / l_r[r];
            const size_t rowoff = base + (size_t)(bq0 + wave * 16 + grp * 4 + r) * H_DIM;
            #pragma unroll
            for (int ht = 0; ht < 4; ++ht)
                out[rowoff + ht * 16 + lid] = o_acc[ht][r] * inv;
        }
    } else {
        const size_t u = ((size_t)b * 64 + qt) * nslots + c;
        #pragma unroll
        for (int r = 0; r < 4; ++r) {
            const int row = wave * 16 + grp * 4 + r;
            #pragma unroll
            for (int ht = 0; ht < 4; ++ht)
                pO[u * 4096 + (size_t)row * 64 + ht * 16 + lid] = o_acc[ht][r];
            if (lid == 0) {
                pm[u * 64 + row] = m_r[r];
                pl[u * 64 + row] = l_r[r];
            }
        }
    }
}

// ---------------------------------------------------------------------------
// Combine partials: out = sum_c O_c * exp(m_c - M) / L.
// Grid (64, 4), 256 threads; thread = (row = t/4, 16-col segment).
// ---------------------------------------------------------------------------
__global__ __launch_bounds__(256) void combine_kernel(
    const float* __restrict__ pO, const float* __restrict__ pm,
    const float* __restrict__ pl, float* __restrict__ out,
    int S, int nslots)
{
    const int qt = blockIdx.x, b = blockIdx.y;
    const int nch = min(nslots, (qt + S) / S);
    const int t = threadIdx.x;
    const int row = t >> 2, seg = (t & 3) * 16;
    const size_t u0 = ((size_t)b * 64 + qt) * nslots;

    float M = -1e30f;
    for (int c = 0; c < nch; ++c)
        M = fmaxf(M, pm[(u0 + c) * 64 + row]);
    float L = 0.f, alpha[4];
    for (int c = 0; c < nch; ++c) {
        alpha[c] = __expf(pm[(u0 + c) * 64 + row] - M);
        L += pl[(u0 + c) * 64 + row] * alpha[c];
    }
    const float inv = 1.f / L;

    float4 o[4] = {};
    for (int c = 0; c < nch; ++c) {
        const float a = alpha[c];
        #pragma unroll
        for (int j = 0; j < 4; ++j) {
            const float4 p = *(const float4*)&pO[(u0 + c) * 4096 +
                                                 (size_t)row * 64 + seg + j * 4];
            o[j].x += p.x * a; o[j].y += p.y * a;
            o[j].z += p.z * a; o[j].w += p.w * a;
        }
    }
    const size_t ob = (size_t)b * T_DIM * H_DIM + (size_t)(qt * 64 + row) * H_DIM + seg;
    #pragma unroll
    for (int j = 0; j < 4; ++j) {
        float4 r;
        r.x = o[j].x * inv; r.y = o[j].y * inv;
        r.z = o[j].z * inv; r.w = o[j].w * inv;
        *(float4*)&out[ob + j * 4] = r;
    }
}

// ---------------------------------------------------------------------------
extern "C" void kernel_launch(void* const* d_in, const int* in_sizes, int n_in,
                              void* d_out, int out_size, void* d_ws, size_t ws_size,
                              hipStream_t stream)
{
    const float* x  = (const float*)d_in[0];
    const float* Wq = (const float*)d_in[1];
    const float* Wk = (const float*)d_in[2];
    const float* Wv = (const float*)d_in[3];
    float* out = (float*)d_out;

    const size_t MB = 1u << 20;
    const size_t n_qkv = (size_t)B_DIM * T_DIM * H_DIM;  // 1M elems
    char* ws = (char*)d_ws;
    ushort* qb  = (ushort*)(ws);            // 2MB
    ushort* kb  = (ushort*)(ws + 2 * MB);   // 2MB
    ushort* vb  = (ushort*)(ws + 4 * MB);   // 2MB
    ushort* wtg = (ushort*)(ws + 6 * MB);   // 384KB
    float*  pO  = (float*)(ws + 7 * MB);    // nslots*4MB
    (void)n_qkv;

    // tier on ws_size (deterministic): partial-O slots
    int nslots, S;
    if      (ws_size >= 24 * MB) { nslots = 4; S = 16; }
    else if (ws_size >= 16 * MB) { nslots = 2; S = 32; }
    else                         { nslots = 1; S = 64; }
    const int direct = (nslots == 1);
    float* pm = pO + (size_t)nslots * 1048576;  // nslots*64KB
    float* pl = pm + (size_t)nslots * 16384;

    hipLaunchKernelGGL(wt_kernel, dim3(96), dim3(256), 0, stream, Wq, Wk, Wv, wtg);
    hipLaunchKernelGGL(qkv_mfma_kernel, dim3((B_DIM * T_DIM) / 32), dim3(256),
                       0, stream, x, wtg, qb, kb, vb);
    hipLaunchKernelGGL(flash_mfma_kernel, dim3(nslots, 64, B_DIM), dim3(256),
                       0, stream, qb, kb, vb, pO, pm, pl, out, S, nslots, direct);
    if (!direct)
        hipLaunchKernelGGL(combine_kernel, dim3(64, B_DIM), dim3(256),
                           0, stream, pO, pm, pl, out, S, nslots);
}

// Round 4
// 83.265 us; speedup vs baseline: 12.4068x; 1.1526x over previous
//
#include <hip/hip_runtime.h>
#include <hip/hip_bf16.h>

// Single causal attention head. B=4, T=4096, C=1024, H=64, fp32 in/out.
// R3: swapped QK^T (lane-local softmax, cvt_pk P-store), T14 reg-prefetch
// staging in flash+qkv, nslots up to 8, qkv M=64 2x2 wave tiling.

#define B_DIM 4
#define T_DIM 4096
#define C_DIM 1024
#define H_DIM 64
#define SCALE 0.03125f  // 1/sqrt(1024)
#define KP 72           // LDS stride (elems): 144B rows, 16B-aligned, balanced banks

typedef __attribute__((ext_vector_type(8))) short bf8;    // 8 bf16
typedef __attribute__((ext_vector_type(4))) float f32x4;  // MFMA acc

__device__ __forceinline__ ushort f2bf(float f) {
    union { float f; uint u; } x; x.f = f;
    const uint u = x.u;
    return (ushort)((u + 0x7FFFu + ((u >> 16) & 1u)) >> 16);  // RNE
}
__device__ __forceinline__ uint cvt_pk_bf16(float lo, float hi) {
    uint r;
    asm("v_cvt_pk_bf16_f32 %0, %1, %2" : "=v"(r) : "v"(lo), "v"(hi));
    return r;
}

// ---------------------------------------------------------------------------
// W^T pre-pass: wtg[col][k], col 0..191 = (Wq|Wk|Wv) columns, bf16.
// ---------------------------------------------------------------------------
__global__ __launch_bounds__(256) void wt_kernel(
    const float* __restrict__ Wq, const float* __restrict__ Wk,
    const float* __restrict__ Wv, ushort* __restrict__ wtg)
{
    const int id  = blockIdx.x * 256 + threadIdx.x;  // 24576 total
    const int col = id >> 7;
    const int k8  = (id & 127) * 8;
    const int m   = col >> 6, lc = col & 63;
    const float* W = (m == 0) ? Wq : (m == 1) ? Wk : Wv;
    ushort o[8];
    #pragma unroll
    for (int i = 0; i < 8; ++i)
        o[i] = f2bf(W[(size_t)(k8 + i) * H_DIM + lc]);
    *(bf8*)&wtg[(size_t)col * C_DIM + k8] = *(bf8*)o;
}

// ---------------------------------------------------------------------------
// QKV projection, bf16 MFMA. Block = 64 rows x 192 cols, 4 waves tiled 2x2
// (wave = 32 rows x 96 cols). K-chunks of 64; reg-prefetch staging (T14).
// ---------------------------------------------------------------------------
__global__ __launch_bounds__(256) void qkv_mfma_kernel(
    const float* __restrict__ x, const ushort* __restrict__ wtg,
    ushort* __restrict__ qo, ushort* __restrict__ ko, ushort* __restrict__ vo)
{
    __shared__ ushort xs[64][KP];
    __shared__ ushort wts[192][KP];
    const int t    = threadIdx.x;
    const int lane = t & 63, wave = t >> 6;
    const int g    = lane >> 4, lid = lane & 15;
    const int wr   = wave >> 1, wc = wave & 1;
    const size_t r0 = (size_t)blockIdx.x * 64;

    f32x4 acc[2][6] = {};

    const int xrow = t >> 2, xcol = (t & 3) * 16;
    float4 xr[4];
    bf8 wreg[6];

    // prefetch kc=0
    #pragma unroll
    for (int i = 0; i < 4; ++i)
        xr[i] = *(const float4*)&x[(r0 + xrow) * C_DIM + xcol + i * 4];
    #pragma unroll
    for (int it = 0; it < 6; ++it) {
        const int n = t + it * 256;
        wreg[it] = *(const bf8*)&wtg[(size_t)(n >> 3) * C_DIM + (n & 7) * 8];
    }

    for (int kc = 0; kc < C_DIM / 64; ++kc) {
        __syncthreads();
        {   // write staged regs to LDS
            uint p[8];
            p[0] = cvt_pk_bf16(xr[0].x, xr[0].y); p[1] = cvt_pk_bf16(xr[0].z, xr[0].w);
            p[2] = cvt_pk_bf16(xr[1].x, xr[1].y); p[3] = cvt_pk_bf16(xr[1].z, xr[1].w);
            p[4] = cvt_pk_bf16(xr[2].x, xr[2].y); p[5] = cvt_pk_bf16(xr[2].z, xr[2].w);
            p[6] = cvt_pk_bf16(xr[3].x, xr[3].y); p[7] = cvt_pk_bf16(xr[3].z, xr[3].w);
            *(bf8*)&xs[xrow][xcol]     = *(bf8*)&p[0];
            *(bf8*)&xs[xrow][xcol + 8] = *(bf8*)&p[4];
            #pragma unroll
            for (int it = 0; it < 6; ++it) {
                const int n = t + it * 256;
                *(bf8*)&wts[n >> 3][(n & 7) * 8] = wreg[it];
            }
        }
        __syncthreads();
        if (kc + 1 < C_DIM / 64) {  // prefetch next chunk
            const int kb = (kc + 1) * 64;
            #pragma unroll
            for (int i = 0; i < 4; ++i)
                xr[i] = *(const float4*)&x[(r0 + xrow) * C_DIM + kb + xcol + i * 4];
            #pragma unroll
            for (int it = 0; it < 6; ++it) {
                const int n = t + it * 256;
                wreg[it] = *(const bf8*)&wtg[(size_t)(n >> 3) * C_DIM + kb + (n & 7) * 8];
            }
        }
        #pragma unroll
        for (int ks = 0; ks < 2; ++ks) {
            const bf8 a0 = *(const bf8*)&xs[wr * 32 + lid][ks * 32 + g * 8];
            const bf8 a1 = *(const bf8*)&xs[wr * 32 + 16 + lid][ks * 32 + g * 8];
            #pragma unroll
            for (int j = 0; j < 6; ++j) {
                const bf8 bb = *(const bf8*)&wts[(wc * 6 + j) * 16 + lid][ks * 32 + g * 8];
                acc[0][j] = __builtin_amdgcn_mfma_f32_16x16x32_bf16(a0, bb, acc[0][j], 0, 0, 0);
                acc[1][j] = __builtin_amdgcn_mfma_f32_16x16x32_bf16(a1, bb, acc[1][j], 0, 0, 0);
            }
        }
    }

    // epilogue: C map col=lid, row=4g+r
    #pragma unroll
    for (int rt = 0; rt < 2; ++rt)
        #pragma unroll
        for (int j = 0; j < 6; ++j) {
            const int ct = wc * 6 + j;
            const int m  = ct >> 2, lc = (ct & 3) * 16 + lid;
            ushort* dst = (m == 0) ? qo : (m == 1) ? ko : vo;
            const float sc = (m == 0) ? SCALE : 1.f;
            #pragma unroll
            for (int r = 0; r < 4; ++r) {
                const size_t row = r0 + wr * 32 + rt * 16 + 4 * g + r;
                dst[row * H_DIM + lc] = f2bf(acc[rt][j][r] * sc);
            }
        }
}

// ---------------------------------------------------------------------------
// Split-K MFMA flash, swapped QK^T (lane-local softmax).
// Grid (nslots, 64, 4). Block = 4 waves x 16 q-rows (QBLK=64), KBLK=64.
// ---------------------------------------------------------------------------
__global__ __launch_bounds__(256) void flash_mfma_kernel(
    const ushort* __restrict__ q, const ushort* __restrict__ k,
    const ushort* __restrict__ v, float* __restrict__ pO,
    float* __restrict__ pm, float* __restrict__ pl,
    float* __restrict__ out, int S, int nslots, int direct)
{
    const int qt = 63 - blockIdx.y;          // heavy q-tiles first
    const int c  = blockIdx.x;
    const int kt_begin = c * S;
    const int kt_end   = min((c + 1) * S, qt + 1);
    if (kt_begin >= kt_end) return;          // inactive chunk (block-uniform)

    __shared__ ushort ks[64][KP];
    __shared__ ushort vt[64][KP];            // vt[h][j] = V[j][h]
    __shared__ ushort ps[4][16][KP];         // per-wave P tile: [q-local][k-local]

    const int t    = threadIdx.x;
    const int lane = t & 63, wave = t >> 6;
    const int g    = lane >> 4, lid = lane & 15;
    const int b    = blockIdx.z;
    const int bq0  = qt * 64;
    const size_t base = (size_t)b * T_DIM * H_DIM;

    // Q fragment (B-operand): lane (g,lid) holds Q[bq0+wave*16+lid][8g..8g+7]
    const size_t qoff = base + (size_t)(bq0 + wave * 16 + lid) * H_DIM;
    const bf8 qf0 = *(const bf8*)&q[qoff + g * 8];
    const bf8 qf1 = *(const bf8*)&q[qoff + 32 + g * 8];

    f32x4 o_acc[4] = {};         // O[q=wave*16+4g+r][h=ht*16+lid]
    float m_run = -1e30f, l_run = 0.f;   // per-lane, q = wave*16+lid

    // prefetch first tile into regs (T14)
    const int krow = t >> 3, kcol = (t & 7) * 8;
    const int vj = (t & 31) * 2, vc = (t >> 5) * 8;
    bf8 kr0, kr1, vr0, vr1;
    {
        const int kg = kt_begin * 64;
        kr0 = *(const bf8*)&k[base + (size_t)(kg + krow) * H_DIM + kcol];
        kr1 = *(const bf8*)&k[base + (size_t)(kg + 32 + krow) * H_DIM + kcol];
        vr0 = *(const bf8*)&v[base + (size_t)(kg + vj) * H_DIM + vc];
        vr1 = *(const bf8*)&v[base + (size_t)(kg + vj + 1) * H_DIM + vc];
    }

    for (int kt64 = kt_begin; kt64 < kt_end; ++kt64) {
        __syncthreads();                 // prev tile LDS reads done
        *(bf8*)&ks[krow][kcol]      = kr0;
        *(bf8*)&ks[32 + krow][kcol] = kr1;
        #pragma unroll
        for (int i = 0; i < 8; ++i) {
            const uint pk = (uint)(ushort)vr0[i] | ((uint)(ushort)vr1[i] << 16);
            *(uint*)&vt[vc + i][vj] = pk;
        }
        __syncthreads();                 // tile ready
        if (kt64 + 1 < kt_end) {         // prefetch next tile under compute
            const int kg = (kt64 + 1) * 64;
            kr0 = *(const bf8*)&k[base + (size_t)(kg + krow) * H_DIM + kcol];
            kr1 = *(const bf8*)&k[base + (size_t)(kg + 32 + krow) * H_DIM + kcol];
            vr0 = *(const bf8*)&v[base + (size_t)(kg + vj) * H_DIM + vc];
            vr1 = *(const bf8*)&v[base + (size_t)(kg + vj + 1) * H_DIM + vc];
        }

        // S^T = mfma(K, Q): lane holds S[q=lid][k = kt*16+4g+r]
        f32x4 st[4];
        #pragma unroll
        for (int kt = 0; kt < 4; ++kt) {
            const bf8 kf0 = *(const bf8*)&ks[kt * 16 + lid][g * 8];
            const bf8 kf1 = *(const bf8*)&ks[kt * 16 + lid][32 + g * 8];
            f32x4 a = {0.f, 0.f, 0.f, 0.f};
            a = __builtin_amdgcn_mfma_f32_16x16x32_bf16(kf0, qf0, a, 0, 0, 0);
            a = __builtin_amdgcn_mfma_f32_16x16x32_bf16(kf1, qf1, a, 0, 0, 0);
            st[kt] = a;
        }

        if (kt64 == qt) {  // diagonal tile: causal mask (kg0 == bq0)
            const int qloc = wave * 16 + lid;
            #pragma unroll
            for (int kt = 0; kt < 4; ++kt)
                #pragma unroll
                for (int r = 0; r < 4; ++r)
                    if (kt * 16 + 4 * g + r > qloc) st[kt][r] = -1e30f;
        }

        // lane-local online softmax (16 values) + cross-group combine
        float mx0 = fmaxf(fmaxf(st[0][0], st[0][1]), fmaxf(st[0][2], st[0][3]));
        float mx1 = fmaxf(fmaxf(st[1][0], st[1][1]), fmaxf(st[1][2], st[1][3]));
        float mx2 = fmaxf(fmaxf(st[2][0], st[2][1]), fmaxf(st[2][2], st[2][3]));
        float mx3 = fmaxf(fmaxf(st[3][0], st[3][1]), fmaxf(st[3][2], st[3][3]));
        float mx = fmaxf(fmaxf(mx0, mx1), fmaxf(mx2, mx3));
        mx = fmaxf(mx, __shfl_xor(mx, 16));
        mx = fmaxf(mx, __shfl_xor(mx, 32));
        const float mnew = fmaxf(m_run, mx);
        const float fsc  = __expf(m_run - mnew);
        m_run = mnew;
        float ls = 0.f;
        #pragma unroll
        for (int kt = 0; kt < 4; ++kt)
            #pragma unroll
            for (int r = 0; r < 4; ++r) {
                const float p = __expf(st[kt][r] - mnew);
                st[kt][r] = p;
                ls += p;
            }
        ls += __shfl_xor(ls, 16);
        ls += __shfl_xor(ls, 32);
        l_run = l_run * fsc + ls;

        // P -> LDS: pack pairs (bf16) and ds_write_b64 per kt
        #pragma unroll
        for (int kt = 0; kt < 4; ++kt) {
            uint2 w;
            w.x = cvt_pk_bf16(st[kt][0], st[kt][1]);
            w.y = cvt_pk_bf16(st[kt][2], st[kt][3]);
            *(uint2*)&ps[wave][lid][kt * 16 + 4 * g] = w;
        }

        // rescale O by f of row q = 4g+r (broadcast from lane 4g+r)
        float fb[4];
        #pragma unroll
        for (int r = 0; r < 4; ++r) fb[r] = __shfl(fsc, 4 * g + r);
        #pragma unroll
        for (int ht = 0; ht < 4; ++ht)
            #pragma unroll
            for (int r = 0; r < 4; ++r) o_acc[ht][r] *= fb[r];

        // PV: A = P[q=lid][8g..], B = V^T[h=ht*16+lid][8g..]
        const bf8 pa0 = *(const bf8*)&ps[wave][lid][g * 8];
        const bf8 pa1 = *(const bf8*)&ps[wave][lid][32 + g * 8];
        #pragma unroll
        for (int ht = 0; ht < 4; ++ht) {
            const bf8 vb0 = *(const bf8*)&vt[ht * 16 + lid][g * 8];
            const bf8 vb1 = *(const bf8*)&vt[ht * 16 + lid][32 + g * 8];
            o_acc[ht] = __builtin_amdgcn_mfma_f32_16x16x32_bf16(pa0, vb0, o_acc[ht], 0, 0, 0);
            o_acc[ht] = __builtin_amdgcn_mfma_f32_16x16x32_bf16(pa1, vb1, o_acc[ht], 0, 0, 0);
        }
    }

    if (direct) {
        float linv[4];
        #pragma unroll
        for (int r = 0; r < 4; ++r) linv[r] = 1.f / __shfl(l_run, 4 * g + r);
        #pragma unroll
        for (int r = 0; r < 4; ++r) {
            const size_t rowoff = base + (size_t)(bq0 + wave * 16 + 4 * g + r) * H_DIM;
            #pragma unroll
            for (int ht = 0; ht < 4; ++ht)
                out[rowoff + ht * 16 + lid] = o_acc[ht][r] * linv[r];
        }
    } else {
        const size_t u = ((size_t)b * 64 + qt) * nslots + c;
        #pragma unroll
        for (int r = 0; r < 4; ++r) {
            const int row = wave * 16 + 4 * g + r;
            #pragma unroll
            for (int ht = 0; ht < 4; ++ht)
                pO[u * 4096 + (size_t)row * 64 + ht * 16 + lid] = o_acc[ht][r];
        }
        if (g == 0) {
            pm[u * 64 + wave * 16 + lid] = m_run;
            pl[u * 64 + wave * 16 + lid] = l_run;
        }
    }
}

// ---------------------------------------------------------------------------
// Combine partials: out = sum_c O_c * exp(m_c - M) / L.
// ---------------------------------------------------------------------------
__global__ __launch_bounds__(256) void combine_kernel(
    const float* __restrict__ pO, const float* __restrict__ pm,
    const float* __restrict__ pl, float* __restrict__ out,
    int S, int nslots)
{
    const int qt = blockIdx.x, b = blockIdx.y;
    const int nch = min(nslots, (qt + S) / S);
    const int t = threadIdx.x;
    const int row = t >> 2, seg = (t & 3) * 16;
    const size_t u0 = ((size_t)b * 64 + qt) * nslots;

    float M = -1e30f;
    for (int c = 0; c < nch; ++c)
        M = fmaxf(M, pm[(u0 + c) * 64 + row]);
    float L = 0.f, alpha[8];
    for (int c = 0; c < nch; ++c) {
        alpha[c] = __expf(pm[(u0 + c) * 64 + row] - M);
        L += pl[(u0 + c) * 64 + row] * alpha[c];
    }
    const float inv = 1.f / L;

    float4 o[4] = {};
    for (int c = 0; c < nch; ++c) {
        const float a = alpha[c];
        #pragma unroll
        for (int j = 0; j < 4; ++j) {
            const float4 p = *(const float4*)&pO[(u0 + c) * 4096 +
                                                 (size_t)row * 64 + seg + j * 4];
            o[j].x += p.x * a; o[j].y += p.y * a;
            o[j].z += p.z * a; o[j].w += p.w * a;
        }
    }
    const size_t ob = (size_t)b * T_DIM * H_DIM + (size_t)(qt * 64 + row) * H_DIM + seg;
    #pragma unroll
    for (int j = 0; j < 4; ++j) {
        float4 r;
        r.x = o[j].x * inv; r.y = o[j].y * inv;
        r.z = o[j].z * inv; r.w = o[j].w * inv;
        *(float4*)&out[ob + j * 4] = r;
    }
}

// ---------------------------------------------------------------------------
extern "C" void kernel_launch(void* const* d_in, const int* in_sizes, int n_in,
                              void* d_out, int out_size, void* d_ws, size_t ws_size,
                              hipStream_t stream)
{
    const float* x  = (const float*)d_in[0];
    const float* Wq = (const float*)d_in[1];
    const float* Wk = (const float*)d_in[2];
    const float* Wv = (const float*)d_in[3];
    float* out = (float*)d_out;

    const size_t MB = 1u << 20;
    char* ws = (char*)d_ws;
    ushort* qb  = (ushort*)(ws);            // 2MB
    ushort* kb  = (ushort*)(ws + 2 * MB);   // 2MB
    ushort* vb  = (ushort*)(ws + 4 * MB);   // 2MB
    ushort* wtg = (ushort*)(ws + 6 * MB);   // 384KB
    float*  pO  = (float*)(ws + 7 * MB);    // nslots*4MB

    int nslots, S;
    if      (ws_size >= 41 * MB) { nslots = 8; S = 8;  }
    else if (ws_size >= 24 * MB) { nslots = 4; S = 16; }
    else if (ws_size >= 16 * MB) { nslots = 2; S = 32; }
    else                         { nslots = 1; S = 64; }
    const int direct = (nslots == 1);
    float* pm = pO + (size_t)nslots * 1048576;  // nslots*64KB
    float* pl = pm + (size_t)nslots * 16384;

    hipLaunchKernelGGL(wt_kernel, dim3(96), dim3(256), 0, stream, Wq, Wk, Wv, wtg);
    hipLaunchKernelGGL(qkv_mfma_kernel, dim3((B_DIM * T_DIM) / 64), dim3(256),
                       0, stream, x, wtg, qb, kb, vb);
    hipLaunchKernelGGL(flash_mfma_kernel, dim3(nslots, 64, B_DIM), dim3(256),
                       0, stream, qb, kb, vb, pO, pm, pl, out, S, nslots, direct);
    if (!direct)
        hipLaunchKernelGGL(combine_kernel, dim3(64, B_DIM), dim3(256),
                           0, stream, pO, pm, pl, out, S, nslots);
}